// Round 1
// baseline (140.383 us; speedup 1.0000x reference)
//
#include <hip/hip_runtime.h>
#include <stdint.h>

// ---------------------------------------------------------------------------
// LinearBlock: out[b, p*8+o] = clip((sum_{q,i} Wq[p,q,o,i]*xq[b,q*8+i])^2, 0, 6)
// Exact int8 path:
//   xq = xu/255,        xu = round(clip(x,0,1)*255)       in [0,255]
//   wq = wi*2/127,      wi = round(clip(w,-2,2)*63.5)     in [-127,127]
//   dot = (sum xu*wi) * 2/(255*127)
// Signed MFMA needs signed A: xs = xu - 128; correction = 128 * rowsum[n].
// ---------------------------------------------------------------------------

typedef int i32x4 __attribute__((ext_vector_type(4)));

#define B_DIM   16384
#define IN_DIM  2048
#define OUT_DIM 2048

__device__ __forceinline__ void async16(const void* g, void* l) {
    __builtin_amdgcn_global_load_lds(
        (const __attribute__((address_space(1))) void*)g,
        (__attribute__((address_space(3))) void*)l, 16, 0, 0);
}

// --- quantize x: float [B,IN] -> int8 (value-128) [B,IN], 16 elems/thread ---
__global__ __launch_bounds__(256) void quant_x_kernel(const float* __restrict__ x,
                                                      int8_t* __restrict__ xq) {
    int i = blockIdx.x * 256 + threadIdx.x;           // 16-elem chunk id
    const float4* xv = (const float4*)x + (size_t)i * 4;
    union { int8_t c[16]; i32x4 v; } u;
#pragma unroll
    for (int j = 0; j < 4; ++j) {
        float4 v = xv[j];
        float f[4] = {v.x, v.y, v.z, v.w};
#pragma unroll
        for (int e = 0; e < 4; ++e) {
            float c = fminf(fmaxf(f[e], 0.0f), 1.0f);
            int q = (int)rintf(c * 255.0f) - 128;
            u.c[j * 4 + e] = (int8_t)q;
        }
    }
    *((i32x4*)xq + i) = u.v;
}

// --- quantize + relayout weight: [P=256,Q=256,8,8] f32 -> [2048][2048] int8
//     row n = p*8+o (output col), col k = q*8+i.  Also rowsum[n] = sum_k wi.
__global__ __launch_bounds__(256) void quant_w_kernel(const float* __restrict__ w,
                                                      int8_t* __restrict__ wq,
                                                      int* __restrict__ rowsum) {
    int p = blockIdx.x;          // 0..255
    int t = threadIdx.x;         // 0..255
    const float* wp = w + (size_t)p * 16384;
    int n = p * 8 + (t & 7);
    int lsum = 0;
#pragma unroll
    for (int s = 0; s < 8; ++s) {
        int g = t + s * 256;                     // 8-elem group id, 0..2047
        float4 v0 = *(const float4*)(wp + g * 8);
        float4 v1 = *(const float4*)(wp + g * 8 + 4);
        float f[8] = {v0.x, v0.y, v0.z, v0.w, v1.x, v1.y, v1.z, v1.w};
        union { int8_t c[8]; long long ll; } u;
#pragma unroll
        for (int e = 0; e < 8; ++e) {
            float c = fminf(fmaxf(f[e], -2.0f), 2.0f);
            int q = (int)rintf(c * 63.5f);       // == round((w/2)*127), exact
            u.c[e] = (int8_t)q;
            lsum += q;
        }
        int kg = g >> 3;                          // k-group: k = kg*8 .. +7
        *(long long*)(wq + (size_t)n * 2048 + kg * 8) = u.ll;
    }
    atomicAdd(&rowsum[n], lsum);
}

// --- int8 GEMM, m97 structure: 128x128 tile, BK=64, 4 waves (2x2), 4x4 frags
__global__ __launch_bounds__(256) void gemm_i8_kernel(const int8_t* __restrict__ A,
                                                      const int8_t* __restrict__ W,
                                                      const int* __restrict__ rowsum,
                                                      float* __restrict__ out) {
    __shared__ int8_t lA[128 * 64];   // 8 KB
    __shared__ int8_t lB[128 * 64];   // 8 KB

    int bid = blockIdx.x;
    int tn = bid & 15;                // 16 col tiles (N=2048/128)
    int tm = bid >> 4;                // 128 row tiles (M=16384/128)
    int brow = tm * 128;
    int bcol = tn * 128;

    int tid  = threadIdx.x;
    int lane = tid & 63;
    int wv   = tid >> 6;
    int wr = wv >> 1, wc = wv & 1;    // 2x2 waves, each 64x64 output
    int l15 = lane & 15;
    int kgb = (lane >> 4) * 16;       // k-group byte offset within 64B row

    i32x4 acc[4][4];
#pragma unroll
    for (int m = 0; m < 4; ++m)
#pragma unroll
        for (int n = 0; n < 4; ++n)
            acc[m][n] = (i32x4){0, 0, 0, 0};

    // staging chunk ids (16B each): tid and tid+256 cover 512 chunks = 8KB
    const int id0 = tid, id1 = tid + 256;
    const size_t aoff0 = (size_t)(brow + (id0 >> 2)) * IN_DIM + ((id0 & 3) << 4);
    const size_t aoff1 = (size_t)(brow + (id1 >> 2)) * IN_DIM + ((id1 & 3) << 4);
    const size_t boff0 = (size_t)(bcol + (id0 >> 2)) * IN_DIM + ((id0 & 3) << 4);
    const size_t boff1 = (size_t)(bcol + (id1 >> 2)) * IN_DIM + ((id1 & 3) << 4);

    for (int kt = 0; kt < IN_DIM / 64; ++kt) {
        const int kb = kt << 6;
        async16(A + aoff0 + kb, lA + id0 * 16);
        async16(A + aoff1 + kb, lA + id1 * 16);
        async16(W + boff0 + kb, lB + id0 * 16);
        async16(W + boff1 + kb, lB + id1 * 16);
        __syncthreads();   // compiler emits vmcnt(0) drain here

        i32x4 af[4], bf[4];
#pragma unroll
        for (int m = 0; m < 4; ++m)
            af[m] = *(const i32x4*)(lA + (wr * 64 + m * 16 + l15) * 64 + kgb);
#pragma unroll
        for (int n = 0; n < 4; ++n)
            bf[n] = *(const i32x4*)(lB + (wc * 64 + n * 16 + l15) * 64 + kgb);

#pragma unroll
        for (int m = 0; m < 4; ++m)
#pragma unroll
            for (int n = 0; n < 4; ++n)
                acc[m][n] = __builtin_amdgcn_mfma_i32_16x16x64_i8(af[m], bf[n],
                                                                  acc[m][n], 0, 0, 0);
        __syncthreads();
    }

    // epilogue: zero-point correction, scale, photodetect square, ReLUN(6)
    const float scale = (float)(2.0 / 32385.0);   // 2/(255*127)
#pragma unroll
    for (int n = 0; n < 4; ++n) {
        int col = bcol + wc * 64 + n * 16 + l15;
        int rs128 = rowsum[col] << 7;             // 128 * sum_k wi[col,k]
#pragma unroll
        for (int m = 0; m < 4; ++m) {
            int row0 = brow + wr * 64 + m * 16 + (lane >> 4) * 4;
#pragma unroll
            for (int r = 0; r < 4; ++r) {
                float f = (float)(acc[m][n][r] + rs128) * scale;
                f = f * f;
                f = fminf(f, 6.0f);
                out[(size_t)(row0 + r) * OUT_DIM + col] = f;
            }
        }
    }
}

extern "C" void kernel_launch(void* const* d_in, const int* in_sizes, int n_in,
                              void* d_out, int out_size, void* d_ws, size_t ws_size,
                              hipStream_t stream) {
    const float* x  = (const float*)d_in[0];   // [16384, 2048] f32
    const float* wt = (const float*)d_in[1];   // [256, 256, 8, 8] f32
    float* out = (float*)d_out;                // [16384, 2048] f32

    char* ws = (char*)d_ws;
    int8_t* xq = (int8_t*)ws;                                   // 32 MB
    int8_t* wq = (int8_t*)(ws + (size_t)B_DIM * IN_DIM);        // 4 MB
    int*    rowsum = (int*)(ws + (size_t)B_DIM * IN_DIM
                               + (size_t)OUT_DIM * IN_DIM);     // 8 KB

    hipMemsetAsync(rowsum, 0, OUT_DIM * sizeof(int), stream);
    quant_x_kernel<<<(B_DIM * IN_DIM / 16) / 256, 256, 0, stream>>>(x, xq);
    quant_w_kernel<<<256, 256, 0, stream>>>(wt, wq, rowsum);
    gemm_i8_kernel<<<(B_DIM / 128) * (OUT_DIM / 128), 256, 0, stream>>>(xq, wq, rowsum, out);
}

// Round 2
// 125.188 us; speedup vs baseline: 1.1214x; 1.1214x over previous
//
#include <hip/hip_runtime.h>
#include <stdint.h>

// ---------------------------------------------------------------------------
// LinearBlock: out[b, p*8+o] = clip((sum_{q,i} Wq[p,q,o,i]*xq[b,q*8+i])^2, 0, 6)
// Exact int8 path:
//   xq = xu/255,        xu = round(clip(x,0,1)*255)       in [0,255]
//   wq = wi*2/127,      wi = round(clip(w,-2,2)*63.5)     in [-127,127]
//   dot = (sum xu*wi) * 2/(255*127)
// Signed MFMA needs signed A: xs = xu - 128; correction = 128 * rowsum[n].
//
// GEMM: 256x256 tile, BK=64, 8 waves (2Mx4N), triple-buffered LDS (96 KB),
// counted vmcnt(4) (never 0 in main loop), 1 barrier/K-tile, XOR chunk
// swizzle (both-sides: pre-swizzled global src for linear gload_lds dest,
// same XOR on ds_read addresses).
// ---------------------------------------------------------------------------

typedef int i32x4 __attribute__((ext_vector_type(4)));

#define B_DIM   16384
#define IN_DIM  2048
#define OUT_DIM 2048

#define BM 256
#define BN 256
#define BK 64
#define KTILES (IN_DIM / BK)        // 32
#define BUFB   (2 * BM * BK)        // 32 KB per buffer (A 16K + B 16K)

__device__ __forceinline__ void async16(const void* g, void* l) {
    __builtin_amdgcn_global_load_lds(
        (const __attribute__((address_space(1))) void*)g,
        (__attribute__((address_space(3))) void*)l, 16, 0, 0);
}

// --- quantize x: float [B,IN] -> int8 (value-128) [B,IN], 16 elems/thread ---
__global__ __launch_bounds__(256) void quant_x_kernel(const float* __restrict__ x,
                                                      int8_t* __restrict__ xq) {
    int i = blockIdx.x * 256 + threadIdx.x;           // 16-elem chunk id
    const float4* xv = (const float4*)x + (size_t)i * 4;
    union { int8_t c[16]; i32x4 v; } u;
#pragma unroll
    for (int j = 0; j < 4; ++j) {
        float4 v = xv[j];
        float f[4] = {v.x, v.y, v.z, v.w};
#pragma unroll
        for (int e = 0; e < 4; ++e) {
            float c = fminf(fmaxf(f[e], 0.0f), 1.0f);
            int q = (int)rintf(c * 255.0f) - 128;
            u.c[j * 4 + e] = (int8_t)q;
        }
    }
    *((i32x4*)xq + i) = u.v;
}

// --- quantize + relayout weight: [P=256,Q=256,8,8] f32 -> [2048][2048] int8
//     row n = p*8+o (output col), col k = q*8+i.  Also rowsum[n] = sum_k wi.
__global__ __launch_bounds__(256) void quant_w_kernel(const float* __restrict__ w,
                                                      int8_t* __restrict__ wq,
                                                      int* __restrict__ rowsum) {
    int p = blockIdx.x;          // 0..255
    int t = threadIdx.x;         // 0..255
    const float* wp = w + (size_t)p * 16384;
    int n = p * 8 + (t & 7);
    int lsum = 0;
#pragma unroll
    for (int s = 0; s < 8; ++s) {
        int g = t + s * 256;                     // 8-elem group id, 0..2047
        float4 v0 = *(const float4*)(wp + g * 8);
        float4 v1 = *(const float4*)(wp + g * 8 + 4);
        float f[8] = {v0.x, v0.y, v0.z, v0.w, v1.x, v1.y, v1.z, v1.w};
        union { int8_t c[8]; long long ll; } u;
#pragma unroll
        for (int e = 0; e < 8; ++e) {
            float c = fminf(fmaxf(f[e], -2.0f), 2.0f);
            int q = (int)rintf(c * 63.5f);       // == round((w/2)*127), exact
            u.c[e] = (int8_t)q;
            lsum += q;
        }
        int kg = g >> 3;                          // k-group: k = kg*8 .. +7
        *(long long*)(wq + (size_t)n * 2048 + kg * 8) = u.ll;
    }
    atomicAdd(&rowsum[n], lsum);
}

// --- int8 GEMM: 256x256 tile, 8 waves, 3-buffer pipeline, counted vmcnt ---
__global__ __launch_bounds__(512, 2) void gemm_i8_kernel(const int8_t* __restrict__ A,
                                                         const int8_t* __restrict__ W,
                                                         const int* __restrict__ rowsum,
                                                         float* __restrict__ out) {
    extern __shared__ int8_t lds[];   // 3 * 32 KB

    // XCD-aware swizzle: 512 wgs, 8 XCDs, 64 contiguous tiles per XCD
    int bid = blockIdx.x;
    int wg = (bid & 7) * 64 + (bid >> 3);
    int tm = wg >> 3;                 // 64 row tiles
    int tn = wg & 7;                  // 8 col tiles
    int brow = tm * BM;
    int bcol = tn * BN;

    int tid  = threadIdx.x;
    int lane = tid & 63;
    int wv   = tid >> 6;
    int wr = wv >> 2, wc = wv & 3;    // 2x4 waves, each 128x64 output
    int l15 = lane & 15;
    int kg  = lane >> 4;              // 0..3

    // --- staging constants (thread stages chunks {tid, tid+512} of A and B)
    // LDS chunk (r, c) holds global chunk (r, c ^ ((r>>1)&3))  [XOR swizzle]
    int r0 = tid >> 2;                // 0..127
    int c0 = tid & 3;
    int sw = ((c0 ^ ((r0 >> 1) & 3)) << 4);
    const int8_t* gA0 = A + (size_t)(brow + r0) * IN_DIM + sw;
    const int8_t* gA1 = A + (size_t)(brow + r0 + 128) * IN_DIM + sw;  // same swizzle: (r0+128)>>1 mod 4 == r0>>1 mod 4
    const int8_t* gB0 = W + (size_t)(bcol + r0) * IN_DIM + sw;
    const int8_t* gB1 = W + (size_t)(bcol + r0 + 128) * IN_DIM + sw;
    const int ldsOff = tid * 16;

    // --- ds_read constants: lane wants (row, k-chunk kg); swizzled chunk is
    //     kg ^ ((row>>1)&3) and (row>>1)&3 == (l15>>1)&3 for all fragments.
    const int koff = ((kg ^ ((l15 >> 1) & 3)) << 4);
    const int aoff = (wr * 128 + l15) * BK + koff;    // + m*16*BK
    const int boff = (wc * 64 + l15) * BK + koff;     // + n*16*BK

    i32x4 acc[8][4];
#pragma unroll
    for (int m = 0; m < 8; ++m)
#pragma unroll
        for (int n = 0; n < 4; ++n)
            acc[m][n] = (i32x4){0, 0, 0, 0};

    auto stage = [&](int bi, int kt) {
        int8_t* la = lds + bi * BUFB;
        int8_t* lb = la + BM * BK;
        const int kb = kt * BK;
        async16(gA0 + kb, la + ldsOff);
        async16(gA1 + kb, la + ldsOff + 8192);
        async16(gB0 + kb, lb + ldsOff);
        async16(gB1 + kb, lb + ldsOff + 8192);
    };

    auto compute = [&](int bi) {
        const int8_t* la = lds + bi * BUFB;
        const int8_t* lb = la + BM * BK;
        i32x4 af[8], bf[4];
#pragma unroll
        for (int m = 0; m < 8; ++m)
            af[m] = *(const i32x4*)(la + aoff + m * (16 * BK));
#pragma unroll
        for (int n = 0; n < 4; ++n)
            bf[n] = *(const i32x4*)(lb + boff + n * (16 * BK));
#pragma unroll
        for (int m = 0; m < 8; ++m)
#pragma unroll
            for (int n = 0; n < 4; ++n)
                acc[m][n] = __builtin_amdgcn_mfma_i32_16x16x64_i8(af[m], bf[n],
                                                                  acc[m][n], 0, 0, 0);
    };

    // prologue: 2 tiles in flight
    stage(0, 0);
    stage(1, 1);

    for (int kt = 0; kt < KTILES - 2; ++kt) {
        // wait own 4 loads for tile kt (4 newer remain in flight), then sync
        asm volatile("s_waitcnt vmcnt(4)" ::: "memory");
        __builtin_amdgcn_s_barrier();
        __builtin_amdgcn_sched_barrier(0);
        // safe: buffer (kt+2)%3 was last read at compute(kt-1), finished by
        // every wave before it arrived at the barrier above.
        stage((kt + 2) % 3, kt + 2);
        compute(kt % 3);
    }
    // kt = KTILES-2: no new stage; last tile's 4 loads still in flight
    asm volatile("s_waitcnt vmcnt(4)" ::: "memory");
    __builtin_amdgcn_s_barrier();
    __builtin_amdgcn_sched_barrier(0);
    compute((KTILES - 2) % 3);
    // kt = KTILES-1: drain
    asm volatile("s_waitcnt vmcnt(0)" ::: "memory");
    __builtin_amdgcn_s_barrier();
    __builtin_amdgcn_sched_barrier(0);
    compute((KTILES - 1) % 3);

    // epilogue: zero-point correction, scale, photodetect square, ReLUN(6)
    const float scale = (float)(2.0 / 32385.0);   // 2/(255*127)
#pragma unroll
    for (int n = 0; n < 4; ++n) {
        int col = bcol + wc * 64 + n * 16 + l15;
        int rs128 = rowsum[col] << 7;             // 128 * sum_k wi[col,k]
#pragma unroll
        for (int m = 0; m < 8; ++m) {
            int row0 = brow + wr * 128 + m * 16 + kg * 4;
#pragma unroll
            for (int r = 0; r < 4; ++r) {
                float f = (float)(acc[m][n][r] + rs128) * scale;
                f = f * f;
                f = fminf(f, 6.0f);
                out[(size_t)(row0 + r) * OUT_DIM + col] = f;
            }
        }
    }
}

extern "C" void kernel_launch(void* const* d_in, const int* in_sizes, int n_in,
                              void* d_out, int out_size, void* d_ws, size_t ws_size,
                              hipStream_t stream) {
    const float* x  = (const float*)d_in[0];   // [16384, 2048] f32
    const float* wt = (const float*)d_in[1];   // [256, 256, 8, 8] f32
    float* out = (float*)d_out;                // [16384, 2048] f32

    char* ws = (char*)d_ws;
    int8_t* xq = (int8_t*)ws;                                   // 32 MB
    int8_t* wq = (int8_t*)(ws + (size_t)B_DIM * IN_DIM);        // 4 MB
    int*    rowsum = (int*)(ws + (size_t)B_DIM * IN_DIM
                               + (size_t)OUT_DIM * IN_DIM);     // 8 KB

    hipMemsetAsync(rowsum, 0, OUT_DIM * sizeof(int), stream);
    quant_x_kernel<<<(B_DIM * IN_DIM / 16) / 256, 256, 0, stream>>>(x, xq);
    quant_w_kernel<<<256, 256, 0, stream>>>(wt, wq, rowsum);
    gemm_i8_kernel<<<(B_DIM / BM) * (OUT_DIM / BN), 512, 3 * BUFB, stream>>>(xq, wq, rowsum, out);
}

// Round 3
// 123.062 us; speedup vs baseline: 1.1408x; 1.0173x over previous
//
#include <hip/hip_runtime.h>
#include <stdint.h>

// ---------------------------------------------------------------------------
// LinearBlock: out[b, p*8+o] = clip((sum_{q,i} Wq[p,q,o,i]*xq[b,q*8+i])^2, 0, 6)
// Exact int8 path:
//   xq = xu/255,        xu = round(clip(x,0,1)*255)       in [0,255]
//   wq = wi*2/127,      wi = round(clip(w,-2,2)*63.5)     in [-127,127]
//   dot = (sum xu*wi) * 2/(255*127)
// Signed MFMA needs signed A: xs = xu - 128; correction = 128 * rowsum[n].
//
// GEMM: 256x256 tile, BK=64, 8 waves (2Mx4N), 3-buffer LDS ring (96 KB),
// m201-style 2-phase-per-K-tile schedule: per phase {ds_read subtile, stage
// 2 gload_lds, barrier, lgkmcnt(0), setprio(1), 16 MFMA, setprio(0),
// barrier}; counted vmcnt(4) once per K-tile (never 0 in main loop).
// XOR chunk swizzle both-sides; XCD-aware block swizzle.
// ---------------------------------------------------------------------------

typedef int i32x4 __attribute__((ext_vector_type(4)));

#define B_DIM   16384
#define IN_DIM  2048
#define OUT_DIM 2048

#define BM 256
#define BN 256
#define BK 64
#define KTILES (IN_DIM / BK)        // 32
#define BUFB   (2 * BM * BK)        // 32 KB per buffer (A 16K + B 16K)

__device__ __forceinline__ void async16(const void* g, void* l) {
    __builtin_amdgcn_global_load_lds(
        (const __attribute__((address_space(1))) void*)g,
        (__attribute__((address_space(3))) void*)l, 16, 0, 0);
}

// --- quantize x: float [B,IN] -> int8 (value-128) [B,IN], 16 elems/thread ---
__global__ __launch_bounds__(256) void quant_x_kernel(const float* __restrict__ x,
                                                      int8_t* __restrict__ xq) {
    int i = blockIdx.x * 256 + threadIdx.x;           // 16-elem chunk id
    const float4* xv = (const float4*)x + (size_t)i * 4;
    union { int8_t c[16]; i32x4 v; } u;
#pragma unroll
    for (int j = 0; j < 4; ++j) {
        float4 v = xv[j];
        float f[4] = {v.x, v.y, v.z, v.w};
#pragma unroll
        for (int e = 0; e < 4; ++e) {
            float c = fminf(fmaxf(f[e], 0.0f), 1.0f);
            int q = (int)rintf(c * 255.0f) - 128;
            u.c[j * 4 + e] = (int8_t)q;
        }
    }
    *((i32x4*)xq + i) = u.v;
}

// --- quantize + relayout weight: [P=256,Q=256,8,8] f32 -> [2048][2048] int8
//     row n = p*8+o (output col), col k = q*8+i.  Also rowsum[n] = sum_k wi.
__global__ __launch_bounds__(256) void quant_w_kernel(const float* __restrict__ w,
                                                      int8_t* __restrict__ wq,
                                                      int* __restrict__ rowsum) {
    int p = blockIdx.x;          // 0..255
    int t = threadIdx.x;         // 0..255
    const float* wp = w + (size_t)p * 16384;
    int n = p * 8 + (t & 7);
    int lsum = 0;
#pragma unroll
    for (int s = 0; s < 8; ++s) {
        int g = t + s * 256;                     // 8-elem group id, 0..2047
        float4 v0 = *(const float4*)(wp + g * 8);
        float4 v1 = *(const float4*)(wp + g * 8 + 4);
        float f[8] = {v0.x, v0.y, v0.z, v0.w, v1.x, v1.y, v1.z, v1.w};
        union { int8_t c[8]; long long ll; } u;
#pragma unroll
        for (int e = 0; e < 8; ++e) {
            float c = fminf(fmaxf(f[e], -2.0f), 2.0f);
            int q = (int)rintf(c * 63.5f);       // == round((w/2)*127), exact
            u.c[e] = (int8_t)q;
            lsum += q;
        }
        int kg = g >> 3;                          // k-group: k = kg*8 .. +7
        *(long long*)(wq + (size_t)n * 2048 + kg * 8) = u.ll;
    }
    atomicAdd(&rowsum[n], lsum);
}

#define MFMA_I8(a, b, c) __builtin_amdgcn_mfma_i32_16x16x64_i8(a, b, c, 0, 0, 0)

// One K-tile: buffer BI (literal), stages tile KT2 into buffer (BI+2)%3.
// WAITN: 4 = steady-state counted wait; 0 = tail drain; -1 = none (last).
#define DO_TILE(BI, KT2, STG, WAITN) do {                                     \
    int8_t* la = lds + (BI) * BUFB;                                           \
    int8_t* lb = la + BM * BK;                                                \
    int8_t* ldst = lds + (((BI) + 2) % 3) * BUFB;                             \
    /* ---- phase 0: read af0-3,bf0-3; stage A of KT2; 16 MFMA ---- */        \
    _Pragma("unroll")                                                         \
    for (int m = 0; m < 4; ++m)                                               \
        af[m] = *(const i32x4*)(la + aoff + m * 1024);                        \
    _Pragma("unroll")                                                         \
    for (int n = 0; n < 4; ++n)                                               \
        bf[n] = *(const i32x4*)(lb + boff + n * 1024);                        \
    if (STG) { const int kb = (KT2) * BK;                                     \
        async16(gA0 + kb, ldst + ldsOff);                                     \
        async16(gA1 + kb, ldst + ldsOff + 8192); }                            \
    __builtin_amdgcn_sched_barrier(0);                                        \
    __builtin_amdgcn_s_barrier();                                             \
    asm volatile("s_waitcnt lgkmcnt(0)" ::: "memory");                        \
    __builtin_amdgcn_sched_barrier(0);                                        \
    __builtin_amdgcn_s_setprio(1);                                            \
    _Pragma("unroll")                                                         \
    for (int m = 0; m < 4; ++m)                                               \
        _Pragma("unroll")                                                     \
        for (int n = 0; n < 4; ++n)                                           \
            acc[m][n] = MFMA_I8(af[m], bf[n], acc[m][n]);                     \
    __builtin_amdgcn_s_setprio(0);                                            \
    __builtin_amdgcn_sched_barrier(0);                                        \
    __builtin_amdgcn_s_barrier();                                             \
    /* ---- phase 1: read af4-7; stage B of KT2; 16 MFMA ---- */              \
    _Pragma("unroll")                                                         \
    for (int m = 4; m < 8; ++m)                                               \
        af[m] = *(const i32x4*)(la + aoff + m * 1024);                        \
    if (STG) { const int kb = (KT2) * BK;                                     \
        async16(gB0 + kb, ldst + BM * BK + ldsOff);                           \
        async16(gB1 + kb, ldst + BM * BK + ldsOff + 8192); }                  \
    __builtin_amdgcn_sched_barrier(0);                                        \
    __builtin_amdgcn_s_barrier();                                             \
    asm volatile("s_waitcnt lgkmcnt(0)" ::: "memory");                        \
    __builtin_amdgcn_sched_barrier(0);                                        \
    __builtin_amdgcn_s_setprio(1);                                            \
    _Pragma("unroll")                                                         \
    for (int m = 4; m < 8; ++m)                                               \
        _Pragma("unroll")                                                     \
        for (int n = 0; n < 4; ++n)                                           \
            acc[m][n] = MFMA_I8(af[m], bf[n], acc[m][n]);                     \
    __builtin_amdgcn_s_setprio(0);                                            \
    __builtin_amdgcn_sched_barrier(0);                                        \
    if ((WAITN) == 4)      asm volatile("s_waitcnt vmcnt(4)" ::: "memory");   \
    else if ((WAITN) == 0) asm volatile("s_waitcnt vmcnt(0)" ::: "memory");   \
    if ((WAITN) >= 0) __builtin_amdgcn_s_barrier();                           \
} while (0)

// --- int8 GEMM: 256x256 tile, 8 waves, 3-buffer ring, 2-phase K-tiles ---
__global__ __launch_bounds__(512, 2) void gemm_i8_kernel(const int8_t* __restrict__ A,
                                                         const int8_t* __restrict__ W,
                                                         const int* __restrict__ rowsum,
                                                         float* __restrict__ out) {
    extern __shared__ int8_t lds[];   // 3 * 32 KB

    // XCD-aware swizzle: 512 wgs, 8 XCDs, 64 contiguous tiles per XCD
    int bid = blockIdx.x;
    int wg = (bid & 7) * 64 + (bid >> 3);
    int tm = wg >> 3;                 // 64 row tiles
    int tn = wg & 7;                  // 8 col tiles
    int brow = tm * BM;
    int bcol = tn * BN;

    int tid  = threadIdx.x;
    int lane = tid & 63;
    int wv   = tid >> 6;
    int wr = wv >> 2, wc = wv & 3;    // 2x4 waves, each 128x64 output
    int l15 = lane & 15;
    int kg  = lane >> 4;              // 0..3

    // --- staging constants (thread stages chunks {tid, tid+512} of A and B)
    // LDS chunk (r, c) holds global chunk (r, c ^ ((r>>1)&3))  [XOR swizzle]
    int r0 = tid >> 2;                // 0..127
    int c0 = tid & 3;
    int sw = ((c0 ^ ((r0 >> 1) & 3)) << 4);
    const int8_t* gA0 = A + (size_t)(brow + r0) * IN_DIM + sw;
    const int8_t* gA1 = A + (size_t)(brow + r0 + 128) * IN_DIM + sw;
    const int8_t* gB0 = W + (size_t)(bcol + r0) * IN_DIM + sw;
    const int8_t* gB1 = W + (size_t)(bcol + r0 + 128) * IN_DIM + sw;
    const int ldsOff = tid * 16;

    // --- ds_read constants: lane wants (row, k-chunk kg); swizzled chunk is
    //     kg ^ ((row>>1)&3) and (row>>1)&3 == (l15>>1)&3 for all fragments.
    const int koff = ((kg ^ ((l15 >> 1) & 3)) << 4);
    const int aoff = (wr * 128 + l15) * BK + koff;    // + m*16*BK (=1024)
    const int boff = (wc * 64 + l15) * BK + koff;     // + n*16*BK

    i32x4 acc[8][4];
#pragma unroll
    for (int m = 0; m < 8; ++m)
#pragma unroll
        for (int n = 0; n < 4; ++n)
            acc[m][n] = (i32x4){0, 0, 0, 0};
    i32x4 af[8], bf[4];

    // --- prologue: stage tile 0 -> buf0, tile 1 -> buf1 (A,A,B,B order) ---
    async16(gA0, lds + ldsOff);
    async16(gA1, lds + ldsOff + 8192);
    async16(gB0, lds + BM * BK + ldsOff);
    async16(gB1, lds + BM * BK + ldsOff + 8192);
    async16(gA0 + BK, lds + BUFB + ldsOff);
    async16(gA1 + BK, lds + BUFB + ldsOff + 8192);
    async16(gB0 + BK, lds + BUFB + BM * BK + ldsOff);
    async16(gB1 + BK, lds + BUFB + BM * BK + ldsOff + 8192);
    asm volatile("s_waitcnt vmcnt(4)" ::: "memory");   // tile 0 landed
    __builtin_amdgcn_s_barrier();

    // --- main loop: tiles 0..29 (each stages tile kt+2), then 2 tails ---
    int kt = 0;
#pragma unroll 1
    for (int t = 0; t < 10; ++t) {
        DO_TILE(0, kt + 2, 1, 4);
        DO_TILE(1, kt + 3, 1, 4);
        DO_TILE(2, kt + 4, 1, 4);
        kt += 3;
    }
    DO_TILE(0, 0, 0, 0);    // tile 30: drain remaining (tile 31) loads
    DO_TILE(1, 0, 0, -1);   // tile 31: no wait needed

    // epilogue: zero-point correction, scale, photodetect square, ReLUN(6)
    const float scale = (float)(2.0 / 32385.0);   // 2/(255*127)
#pragma unroll
    for (int n = 0; n < 4; ++n) {
        int col = bcol + wc * 64 + n * 16 + l15;
        int rs128 = rowsum[col] << 7;             // 128 * sum_k wi[col,k]
#pragma unroll
        for (int m = 0; m < 8; ++m) {
            int row0 = brow + wr * 128 + m * 16 + kg * 4;
#pragma unroll
            for (int r = 0; r < 4; ++r) {
                float f = (float)(acc[m][n][r] + rs128) * scale;
                f = f * f;
                f = fminf(f, 6.0f);
                out[(size_t)(row0 + r) * OUT_DIM + col] = f;
            }
        }
    }
}

extern "C" void kernel_launch(void* const* d_in, const int* in_sizes, int n_in,
                              void* d_out, int out_size, void* d_ws, size_t ws_size,
                              hipStream_t stream) {
    const float* x  = (const float*)d_in[0];   // [16384, 2048] f32
    const float* wt = (const float*)d_in[1];   // [256, 256, 8, 8] f32
    float* out = (float*)d_out;                // [16384, 2048] f32

    char* ws = (char*)d_ws;
    int8_t* xq = (int8_t*)ws;                                   // 32 MB
    int8_t* wq = (int8_t*)(ws + (size_t)B_DIM * IN_DIM);        // 4 MB
    int*    rowsum = (int*)(ws + (size_t)B_DIM * IN_DIM
                               + (size_t)OUT_DIM * IN_DIM);     // 8 KB

    hipMemsetAsync(rowsum, 0, OUT_DIM * sizeof(int), stream);
    quant_x_kernel<<<(B_DIM * IN_DIM / 16) / 256, 256, 0, stream>>>(x, xq);
    quant_w_kernel<<<256, 256, 0, stream>>>(wt, wq, rowsum);
    gemm_i8_kernel<<<(B_DIM / BM) * (OUT_DIM / BN), 512, 3 * BUFB, stream>>>(xq, wq, rowsum, out);
}